// Round 13
// baseline (383.773 us; speedup 1.0000x reference)
//
#include <hip/hip_runtime.h>
#include <hip/hip_fp16.h>

static constexpr int NN = 100000;
static constexpr int NE = 3200000;
static constexpr int NG = 512;
static constexpr int NCB = 196;                       // coarse bins: 512 nodes (dst>>9)
static constexpr int CHK = 8192;
static constexpr int NCH = (NE + CHK - 1) / CHK;      // 391 chunks
static constexpr int NCNT = NCB * NCH;                // 76636 count cells
static constexpr int SCAN_BLK = 2048;
static constexpr int NSB = (NCNT + SCAN_BLK - 1) / SCAN_BLK;  // 38
static constexpr int CAPE = 24576;                    // 96KB LDS edge buffer/bin
static constexpr int T3GRID = 1048;                   // pull3 blocks (mult of 8)

// Session ledger:
//  R5: NT scattered stores -> 9x write amp. R6: NT csr loads bypass L1 -> +46%.
//  R7: W from global -> +38%. R8: low-LDS small blocks -> worse. R10: LPT
//  degree-order null. Schedule levers exhausted: pulls bound by L2-miss count
//  (FETCH ~= 18x table re-fetch: 8 XCD L2s each thrash the whole 4.8MB table).
//  R11 (327us): fill512 single-read LDS + poolhead 32-row MLP (+9us).
//  R12: H3 stored as 3 PLANES of 1.6MB; pull3 slice=(bid%8)%3 pins each XCD's
//  gathers to one plane (fits its private L2). GEMM split off (fp16 G interm).
typedef float f32x2 __attribute__((ext_vector_type(2)));

__device__ __forceinline__ void set2_fp8x4(unsigned v, f32x2* a) {
    a[0] = __builtin_amdgcn_cvt_pk_f32_fp8((int)v, false);
    a[1] = __builtin_amdgcn_cvt_pk_f32_fp8((int)v, true);
}
__device__ __forceinline__ void acc2_fp8x4(unsigned v, f32x2* a) {
    a[0] += __builtin_amdgcn_cvt_pk_f32_fp8((int)v, false);   // v_pk_add_f32
    a[1] += __builtin_amdgcn_cvt_pk_f32_fp8((int)v, true);
}
__device__ __forceinline__ unsigned pack_fp8x4(float a, float b, float c, float d) {
    int p = __builtin_amdgcn_cvt_pk_fp8_f32(a, b, 0, false);
    p = __builtin_amdgcn_cvt_pk_fp8_f32(c, d, p, true);
    return (unsigned)p;
}
__device__ __forceinline__ unsigned pkh2(float a, float b) {
    __half2 h = __floats2half2_rn(a, b);
    return *(unsigned*)&h;
}

// ---- per-chunk coarse histogram (int4 dst stream): cntC[bin*NCH + chunk] ---
__global__ __launch_bounds__(256) void k_histC(const int4* __restrict__ dst4,
                                               int* __restrict__ cntC, int e4) {
    __shared__ int h[NCB];
    for (int i = threadIdx.x; i < NCB; i += 256) h[i] = 0;
    __syncthreads();
    const int s4 = blockIdx.x * (CHK / 4), e4end = min(s4 + CHK / 4, e4);
    for (int i = s4 + threadIdx.x; i < e4end; i += 256) {
        int4 d = dst4[i];
        atomicAdd(&h[d.x >> 9], 1);
        atomicAdd(&h[d.y >> 9], 1);
        atomicAdd(&h[d.z >> 9], 1);
        atomicAdd(&h[d.w >> 9], 1);
    }
    __syncthreads();
    for (int i = threadIdx.x; i < NCB; i += 256)
        cntC[(size_t)i * NCH + blockIdx.x] = h[i];
}

// ---- 2-kernel exclusive scan (block-local + bsum scan; add folded later) ---
__global__ __launch_bounds__(256) void k_scanA(const int* __restrict__ in,
                                               int* __restrict__ out,
                                               int* __restrict__ bsum, int n) {
    __shared__ int s[256];
    const int tid = threadIdx.x;
    const int base = blockIdx.x * SCAN_BLK + tid * 8;
    int v[8], t = 0;
#pragma unroll
    for (int c = 0; c < 8; c++) {
        int idx = base + c;
        v[c] = (idx < n) ? in[idx] : 0;
        t += v[c];
    }
    s[tid] = t;
    __syncthreads();
    for (int off = 1; off < 256; off <<= 1) {
        int x = (tid >= off) ? s[tid - off] : 0;
        __syncthreads();
        s[tid] += x;
        __syncthreads();
    }
    if (tid == 255) bsum[blockIdx.x] = s[255];
    int run = s[tid] - t;
#pragma unroll
    for (int c = 0; c < 8; c++) {
        int idx = base + c;
        if (idx < n) out[idx] = run;
        run += v[c];
    }
}

__global__ __launch_bounds__(256) void k_scanB(int* __restrict__ bsum, int nb) {
    __shared__ int s[256];
    const int tid = threadIdx.x;
    int v = (tid < nb) ? bsum[tid] : 0;
    s[tid] = v;
    __syncthreads();
    for (int off = 1; off < 256; off <<= 1) {
        int x = (tid >= off) ? s[tid - off] : 0;
        __syncthreads();
        s[tid] += x;
        __syncthreads();
    }
    if (tid < nb) bsum[tid] = s[tid] - v;
}

// ---- coarse scatter (int4 streams): tmp[pos] = (dst&511)<<17 | src ---------
__global__ __launch_bounds__(256) void k_scatC(const int4* __restrict__ src4,
                                               const int4* __restrict__ dst4,
                                               const int* __restrict__ sc,
                                               const int* __restrict__ bsum,
                                               unsigned* __restrict__ tmp, int e4) {
    __shared__ int cur[NCB];
    for (int i = threadIdx.x; i < NCB; i += 256) {
        size_t idx = (size_t)i * NCH + blockIdx.x;
        cur[i] = sc[idx] + bsum[idx >> 11];
    }
    __syncthreads();
    const int s4 = blockIdx.x * (CHK / 4), e4end = min(s4 + CHK / 4, e4);
    for (int i = s4 + threadIdx.x; i < e4end; i += 256) {
        int4 d = dst4[i];
        int4 sv = src4[i];
        int p0 = atomicAdd(&cur[d.x >> 9], 1);
        tmp[p0] = ((unsigned)(d.x & 511) << 17) | (unsigned)sv.x;
        int p1 = atomicAdd(&cur[d.y >> 9], 1);
        tmp[p1] = ((unsigned)(d.y & 511) << 17) | (unsigned)sv.y;
        int p2 = atomicAdd(&cur[d.z >> 9], 1);
        tmp[p2] = ((unsigned)(d.z & 511) << 17) | (unsigned)sv.z;
        int p3 = atomicAdd(&cur[d.w >> 9], 1);
        tmp[p3] = ((unsigned)(d.w & 511) << 17) | (unsigned)sv.w;
    }
}

// ---- per-bin (512 nodes): single global read into LDS; count/scan/scatter --
__global__ __launch_bounds__(1024) void k_fill512(const unsigned* __restrict__ tmp,
                                                  const int* __restrict__ sc,
                                                  const int* __restrict__ bsum,
                                                  int* __restrict__ csr,
                                                  int* __restrict__ degi,
                                                  int* __restrict__ offs,
                                                  float* __restrict__ dis,
                                                  int n, int etotal) {
    __shared__ unsigned eL[CAPE];   // 96 KB edge cache
    __shared__ int cnt[512];
    __shared__ int s[512];
    __shared__ int cur[512];
    const int b = blockIdx.x, tid = threadIdx.x;
    if (tid < 512) cnt[tid] = 0;
    size_t i0 = (size_t)b * NCH;
    const int e0 = sc[i0] + bsum[i0 >> 11];
    int e1 = etotal;
    if (b + 1 < NCB) {
        size_t i1 = (size_t)(b + 1) * NCH;
        e1 = sc[i1] + bsum[i1 >> 11];
    }
    const int m = e1 - e0;
    const bool fits = (m <= CAPE);
    __syncthreads();
    if (fits) {
        for (int i = tid; i < m; i += 1024) {     // one global pass: load+count
            unsigned pk = tmp[e0 + i];
            eL[i] = pk;
            atomicAdd(&cnt[pk >> 17], 1);
        }
    } else {
        for (int e = e0 + tid; e < e1; e += 1024)
            atomicAdd(&cnt[tmp[e] >> 17], 1);
    }
    __syncthreads();
    int v = 0;
    if (tid < 512) { v = cnt[tid]; s[tid] = v; }
    __syncthreads();
    for (int off = 1; off < 512; off <<= 1) {
        int x = 0;
        if (tid < 512 && tid >= off) x = s[tid - off];
        __syncthreads();
        if (tid < 512) s[tid] += x;
        __syncthreads();
    }
    if (tid < 512) {
        int c = e0 + s[tid] - v;   // exclusive prefix within bin window
        cur[tid] = c;
        int node = b * 512 + tid;
        if (node < n) {
            degi[node] = v;
            offs[node] = c;
            dis[node] = rsqrtf((float)v + 1.0f);
        }
    }
    __syncthreads();
    if (fits) {
        for (int i = tid; i < m; i += 1024) {
            unsigned pk = eL[i];
            int p = atomicAdd(&cur[pk >> 17], 1);
            csr[p] = (int)(pk & 0x1FFFFu);
        }
    } else {
        for (int e = e0 + tid; e < e1; e += 1024) {
            unsigned pk = tmp[e];
            int p = atomicAdd(&cur[pk >> 17], 1);
            csr[p] = (int)(pk & 0x1FFFFu);
        }
    }
}

// ---- gemm1: H1' = fp8((x @ W1) * dis[row])  (128 -> 32) --------------------
__global__ __launch_bounds__(256) void k_gemm1(const float* __restrict__ X,
                                               const float* __restrict__ W,
                                               const float* __restrict__ dis,
                                               unsigned* __restrict__ H, int n) {
    constexpr int IN = 128, ROWS = 32;
    __shared__ float sW[IN * 32];
    __shared__ float sX[ROWS][IN];
    const int tid = threadIdx.x;
    for (int i = tid; i < IN * 32; i += 256) sW[i] = W[i];
    const int row0 = blockIdx.x * ROWS;
    const float4* X4 = (const float4*)X;
    for (int i = tid; i < ROWS * 32; i += 256) {
        int r = row0 + (i >> 5);
        float4 v = make_float4(0.f, 0.f, 0.f, 0.f);
        if (r < n) v = X4[(size_t)r * 32 + (i & 31)];
        ((float4*)&sX[i >> 5][0])[i & 31] = v;
    }
    __syncthreads();
    const int lr = tid >> 3;        // local row
    const int cg = tid & 7;         // col group (4 cols)
    const int gr = row0 + lr;
    float acc[4] = {0.f, 0.f, 0.f, 0.f};
#pragma unroll 8
    for (int k = 0; k < IN; k++) {
        float xv = sX[lr][k];
#pragma unroll
        for (int c = 0; c < 4; c++)
            acc[c] = fmaf(xv, sW[k * 32 + 4 * cg + c], acc[c]);
    }
    if (gr < n) {
        float dd = dis[gr];
        H[(size_t)gr * 8 + cg] =
            pack_fp8x4(acc[0] * dd, acc[1] * dd, acc[2] * dd, acc[3] * dd);
    }
}

// ---- layer-1 pull (32-dim fp8): 4 lanes/node, predicated 8-wide gathers ----
// out = fp8(relu(dis*(self+sum)+b) * dis)
__global__ __launch_bounds__(256) void k_pull2(
        const uint2* __restrict__ Hp, const int* __restrict__ offs,
        const int* __restrict__ degi, const int* __restrict__ csr,
        const float* __restrict__ dis, const float* __restrict__ b,
        uint2* __restrict__ A, int n) {
    const int group = threadIdx.x >> 2, j0 = threadIdx.x & 3;
    const int d = blockIdx.x * 64 + group;
    if (d >= n) return;
    f32x2 acc[4];
    uint2 sv = Hp[(size_t)d * 4 + j0];
    set2_fp8x4(sv.x, acc); set2_fp8x4(sv.y, acc + 2);
    int e = offs[d];
    const int end = e + degi[d];
    for (; e < end; e += 8) {
        uint2 v[8];
#pragma unroll
        for (int i = 0; i < 8; i++) {
            int ee = e + i;
            int idx = csr[min(ee, NE - 1)];
            uint2 t = Hp[(size_t)idx * 4 + j0];
            if (ee >= end) { t.x = 0u; t.y = 0u; }   // fp8 0x00 == +0.0
            v[i] = t;
        }
#pragma unroll
        for (int i = 0; i < 8; i++) {
            acc2_fp8x4(v[i].x, acc); acc2_fp8x4(v[i].y, acc + 2);
        }
    }
    const float dd = dis[d];
    float r[8];
#pragma unroll
    for (int c = 0; c < 4; c++) {
        r[2 * c]     = fmaxf(fmaf(acc[c].x, dd, b[8 * j0 + 2 * c]), 0.f) * dd;
        r[2 * c + 1] = fmaxf(fmaf(acc[c].y, dd, b[8 * j0 + 2 * c + 1]), 0.f) * dd;
    }
    A[(size_t)d * 4 + j0] = make_uint2(pack_fp8x4(r[0], r[1], r[2], r[3]),
                                       pack_fp8x4(r[4], r[5], r[6], r[7]));
}

// ---- layer-2: pull(32 fp8) + fused gemm 32->48 -> fp8 PLANAR H3 ------------
// R4 structure; output now 3 planes of NN x 16B (for XCD-sliced layer-3 pull)
__global__ __launch_bounds__(256) void k_pullmm32(
        const uint2* __restrict__ Hp, const int* __restrict__ offs,
        const int* __restrict__ degi, const int* __restrict__ csr,
        const float* __restrict__ dis, const float* __restrict__ W,
        const float* __restrict__ b, unsigned* __restrict__ A, int n) {
    __shared__ float sW[32 * 48];    // 6 KB
    __shared__ float rows[64][33];   // 8.25 KB
    for (int i = threadIdx.x; i < 32 * 48; i += 256) sW[i] = W[i];
    const int group = threadIdx.x >> 2, j0 = threadIdx.x & 3;
    const int d = blockIdx.x * 64 + group;
    if (d < n) {
        f32x2 acc[4];
        uint2 sv = Hp[(size_t)d * 4 + j0];
        set2_fp8x4(sv.x, acc); set2_fp8x4(sv.y, acc + 2);
        int e = offs[d];
        const int end = e + degi[d];
        for (; e < end; e += 8) {
            uint2 v[8];
#pragma unroll
            for (int i = 0; i < 8; i++) {
                int ee = e + i;
                int idx = csr[min(ee, NE - 1)];
                uint2 t = Hp[(size_t)idx * 4 + j0];
                if (ee >= end) { t.x = 0u; t.y = 0u; }
                v[i] = t;
            }
#pragma unroll
            for (int i = 0; i < 8; i++) {
                acc2_fp8x4(v[i].x, acc); acc2_fp8x4(v[i].y, acc + 2);
            }
        }
        const float dd = dis[d];
#pragma unroll
        for (int c = 0; c < 4; c++) {
            rows[group][8 * j0 + 2 * c]     = acc[c].x * dd;
            rows[group][8 * j0 + 2 * c + 1] = acc[c].y * dd;
        }
    }
    __syncthreads();
    const int row0 = blockIdx.x * 64;
    const int nl = threadIdx.x & 63, cgb = threadIdx.x >> 6;  // row, col-block
    const int gr = row0 + nl;
    if (gr < n) {
        const float4* sW4 = (const float4*)sW;
        float s[3][4];
#pragma unroll
        for (int o = 0; o < 3; o++)
#pragma unroll
            for (int c = 0; c < 4; c++) s[o][c] = b[12 * cgb + 4 * o + c];
#pragma unroll 8
        for (int k = 0; k < 32; k++) {
            float rv = rows[nl][k];
#pragma unroll
            for (int o = 0; o < 3; o++) {
                float4 w = sW4[k * 12 + cgb * 3 + o];   // wave-uniform broadcast
                s[o][0] = fmaf(rv, w.x, s[o][0]);
                s[o][1] = fmaf(rv, w.y, s[o][1]);
                s[o][2] = fmaf(rv, w.z, s[o][2]);
                s[o][3] = fmaf(rv, w.w, s[o][3]);
            }
        }
        const float dd2 = dis[gr];
#pragma unroll
        for (int o = 0; o < 3; o++) {
            float r0 = fmaxf(s[o][0], 0.f) * dd2;
            float r1 = fmaxf(s[o][1], 0.f) * dd2;
            float r2 = fmaxf(s[o][2], 0.f) * dd2;
            float r3 = fmaxf(s[o][3], 0.f) * dd2;
            int w = cgb * 3 + o;              // word 0..11, cols 4w..4w+3
            A[(size_t)(w >> 2) * NN * 4 + (size_t)gr * 4 + (w & 3)] =
                pack_fp8x4(r0, r1, r2, r3);   // plane w>>2, word w&3
        }
    }
}

// ---- layer-3 pull, XCD-sliced planar: slice=(bid%8)%3 -> one 1.6MB plane ---
// 1 thread/node/slice, uint4 gathers, 8-deep predicated; G = fp16 sums x dis
__global__ __launch_bounds__(256) void k_pull3(
        const unsigned* __restrict__ H3,   // 3 planes of NN*4 uints
        const int* __restrict__ offs, const int* __restrict__ degi,
        const int* __restrict__ csr, const float* __restrict__ dis,
        unsigned* __restrict__ G0, unsigned* __restrict__ G1,
        unsigned* __restrict__ G2, int n) {
    const int s8 = blockIdx.x & 7;
    const int slice = s8 % 3;                       // XCDs {0,3,6},{1,4,7},{2,5}
    const int cnt = (slice < 2) ? 3 : 2;
    const int rank = (blockIdx.x >> 3) * cnt + (s8 - slice) / 3;
    const int stride = (int)(gridDim.x >> 3) * cnt * 256;
    const uint4* P = (const uint4*)(H3 + (size_t)slice * NN * 4);
    unsigned* G = (slice == 0) ? G0 : (slice == 1) ? G1 : G2;
    for (int d = rank * 256 + threadIdx.x; d < n; d += stride) {
        f32x2 acc[8];
        uint4 sv = P[d];
        set2_fp8x4(sv.x, acc);     set2_fp8x4(sv.y, acc + 2);
        set2_fp8x4(sv.z, acc + 4); set2_fp8x4(sv.w, acc + 6);
        int e = offs[d];
        const int end = e + degi[d];
        for (; e < end; e += 8) {
            uint4 v[8];
#pragma unroll
            for (int i = 0; i < 8; i++) {
                int ee = e + i;
                int idx = csr[min(ee, NE - 1)];
                uint4 t = P[idx];
                if (ee >= end) { t.x = 0u; t.y = 0u; t.z = 0u; t.w = 0u; }
                v[i] = t;
            }
#pragma unroll
            for (int i = 0; i < 8; i++) {
                acc2_fp8x4(v[i].x, acc);     acc2_fp8x4(v[i].y, acc + 2);
                acc2_fp8x4(v[i].z, acc + 4); acc2_fp8x4(v[i].w, acc + 6);
            }
        }
        const float dd = dis[d];
        unsigned g[8];
#pragma unroll
        for (int j = 0; j < 8; j++)
            g[j] = pkh2(acc[j].x * dd, acc[j].y * dd);
        uint4* Gq = (uint4*)(G + (size_t)d * 8);
        Gq[0] = make_uint4(g[0], g[1], g[2], g[3]);
        Gq[1] = make_uint4(g[4], g[5], g[6], g[7]);
    }
}

// ---- layer-3 GEMM 48->64 from fp16 G planes -> A3 fp16 ---------------------
__global__ __launch_bounds__(256) void k_mm48(
        const unsigned* __restrict__ G0, const unsigned* __restrict__ G1,
        const unsigned* __restrict__ G2, const float* __restrict__ W,
        const float* __restrict__ b, __half* __restrict__ A, int n) {
    __shared__ float sW[48 * 64];   // 12 KB
    __shared__ float rows[64][49];  // 12.25 KB
    for (int i = threadIdx.x; i < 48 * 64; i += 256) sW[i] = W[i];
    const int row0 = blockIdx.x * 64;
    for (int i = threadIdx.x; i < 64 * 24; i += 256) {
        int nl = i / 24, w = i % 24;
        int pl = w >> 3, j = w & 7;
        int node = row0 + nl;
        if (node < n) {
            const unsigned* gp = (pl == 0) ? G0 : (pl == 1) ? G1 : G2;
            unsigned u = gp[(size_t)node * 8 + j];
            __half2 h2 = *(__half2*)&u;
            float2 f = __half22float2(h2);
            rows[nl][pl * 16 + 2 * j]     = f.x;
            rows[nl][pl * 16 + 2 * j + 1] = f.y;
        }
    }
    __syncthreads();
    const int nl = threadIdx.x & 63, cgb = threadIdx.x >> 6;  // row, 16-col block
    const int gr = row0 + nl;
    if (gr < n) {
        const float4* sW4 = (const float4*)sW;
        float s[4][4];
#pragma unroll
        for (int o = 0; o < 4; o++)
#pragma unroll
            for (int c = 0; c < 4; c++) s[o][c] = b[16 * cgb + 4 * o + c];
#pragma unroll 8
        for (int k = 0; k < 48; k++) {
            float rv = rows[nl][k];
#pragma unroll
            for (int o = 0; o < 4; o++) {
                float4 w = sW4[k * 16 + cgb * 4 + o];   // wave-uniform broadcast
                s[o][0] = fmaf(rv, w.x, s[o][0]);
                s[o][1] = fmaf(rv, w.y, s[o][1]);
                s[o][2] = fmaf(rv, w.z, s[o][2]);
                s[o][3] = fmaf(rv, w.w, s[o][3]);
            }
        }
        uint4 q0, q1;
        q0.x = pkh2(s[0][0], s[0][1]); q0.y = pkh2(s[0][2], s[0][3]);
        q0.z = pkh2(s[1][0], s[1][1]); q0.w = pkh2(s[1][2], s[1][3]);
        q1.x = pkh2(s[2][0], s[2][1]); q1.y = pkh2(s[2][2], s[2][3]);
        q1.z = pkh2(s[3][0], s[3][1]); q1.w = pkh2(s[3][2], s[3][3]);
        ((uint4*)A)[(size_t)gr * 8 + cgb * 2]     = q0;
        ((uint4*)A)[(size_t)gr * 8 + cgb * 2 + 1] = q1;
    }
}

// ---- fused: bounds + mean-pool (32 rows in flight) + MLP head + softmax ----
__global__ __launch_bounds__(256) void k_poolhead(
        const __half* __restrict__ A3, const int* __restrict__ batch,
        const float* __restrict__ f1w, const float* __restrict__ f1b,
        const float* __restrict__ f2w, const float* __restrict__ f2b,
        float* __restrict__ out, int n, int ngr) {
    const int g = blockIdx.x;
    __shared__ int sb[2];
    if (threadIdx.x < 2) {
        int target = g + threadIdx.x;
        int lo = 0, hi = n;
        while (lo < hi) {
            int mid = (lo + hi) >> 1;
            if (batch[mid] < target) lo = mid + 1; else hi = mid;
        }
        sb[threadIdx.x] = lo;
    }
    __syncthreads();
    const int s = sb[0], e = sb[1];
    const int cg8 = threadIdx.x & 7;      // col-group (8 halves)
    const int rr  = threadIdx.x >> 3;     // 0..31 row offset
    float sum[8] = {0.f, 0.f, 0.f, 0.f, 0.f, 0.f, 0.f, 0.f};
    for (int node = s + rr; node < e; node += 32) {
        uint4 v = *(const uint4*)(A3 + (size_t)node * 64 + cg8 * 8);
        unsigned w[4] = {v.x, v.y, v.z, v.w};
#pragma unroll
        for (int h = 0; h < 4; h++) {
            __half2 h2 = *(__half2*)&w[h];
            float2 f = __half22float2(h2);
            sum[2 * h]     += fmaxf(f.x, 0.f);
            sum[2 * h + 1] += fmaxf(f.y, 0.f);
        }
    }
    __shared__ float red[32][64];
#pragma unroll
    for (int h = 0; h < 8; h++) red[rr][cg8 * 8 + h] = sum[h];
    __syncthreads();
    __shared__ float p[64], z[32], lg[16];
    const int t = threadIdx.x;
    if (t < 64) {
        float acc = 0.f;
#pragma unroll 8
        for (int r = 0; r < 32; r++) acc += red[r][t];
        p[t] = acc / fmaxf((float)(e - s), 1.f);
    }
    __syncthreads();
    if (t < 32) {
        float acc = f1b[t];
        for (int k = 0; k < 64; k++) acc = fmaf(p[k], f1w[k * 32 + t], acc);
        z[t] = fmaxf(acc, 0.f);
    }
    __syncthreads();
    if (t < 16) {
        float acc = f2b[t];
        for (int k = 0; k < 32; k++) acc = fmaf(z[k], f2w[k * 16 + t], acc);
        lg[t] = acc;
    }
    __syncthreads();
    if (t < 16) {
        float m = lg[0];
        for (int i = 1; i < 16; i++) m = fmaxf(m, lg[i]);
        float sden = 0.f;
        for (int i = 0; i < 16; i++) sden += expf(lg[i] - m);
        out[g * 16 + t] = expf(lg[t] - m) / sden;
    }
}

extern "C" void kernel_launch(void* const* d_in, const int* in_sizes, int n_in,
                              void* d_out, int out_size, void* d_ws, size_t ws_size,
                              hipStream_t stream) {
    (void)in_sizes; (void)n_in; (void)out_size; (void)ws_size;
    const float* x     = (const float*)d_in[0];
    const int*   ei    = (const int*)d_in[1];
    const int*   batch = (const int*)d_in[2];
    const float* W1 = (const float*)d_in[3];
    const float* b1 = (const float*)d_in[4];
    const float* W2 = (const float*)d_in[5];  const float* b2 = (const float*)d_in[6];
    const float* W3 = (const float*)d_in[7];  const float* b3 = (const float*)d_in[8];
    const float* f1w = (const float*)d_in[9]; const float* f1b = (const float*)d_in[10];
    const float* f2w = (const float*)d_in[11];const float* f2b = (const float*)d_in[12];
    float* out = (float*)d_out;

    const int* src = ei;
    const int* dst = ei + NE;

    // Workspace (~42 MB):
    //   tmp uint[NE] (12.8MB) aliased with A3 fp16[NN*64] (12.8MB)
    //   H1/H2 fp8 (3.2MB each; reused as G planes 0/1 after their layers)
    //   H3 planar fp8 3x1.6MB (4.8MB); G2 fp16 plane (3.2MB)
    float* ws = (float*)d_ws;
    size_t o = 0;
    float* dis    = ws + o; o += NN;
    int*   degi   = (int*)(ws + o); o += NN;
    int*   offs   = (int*)(ws + o); o += NN;
    int*   cntC   = (int*)(ws + o); o += 76640;       // NCNT padded to /16
    int*   sc     = (int*)(ws + o); o += 76640;
    int*   bsum   = (int*)(ws + o); o += 48;
    int*   csr    = (int*)(ws + o); o += NE;
    unsigned* TA  = (unsigned*)(ws + o); o += NE;     // tmp | A3
    unsigned* H1  = (unsigned*)(ws + o); o += NN * 8;
    unsigned* H2  = (unsigned*)(ws + o); o += NN * 8;
    unsigned* H3  = (unsigned*)(ws + o); o += NN * 12;  // 3 planes x NN*4 uints
    unsigned* G2  = (unsigned*)(ws + o); o += NN * 8;   // fp16 G plane 2

    unsigned* tmp = (unsigned*)TA;
    __half*   A3  = (__half*)TA;
    unsigned* G0  = H1;   // dead after k_pull2
    unsigned* G1  = H2;   // dead after k_pullmm32

    // CSR build: coarse counting sort (196 bins x 512 nodes) + in-LDS sub-sort
    k_histC<<<NCH, 256, 0, stream>>>((const int4*)dst, cntC, NE / 4);
    k_scanA<<<NSB, 256, 0, stream>>>(cntC, sc, bsum, NCNT);
    k_scanB<<<1, 256, 0, stream>>>(bsum, NSB);
    k_scatC<<<NCH, 256, 0, stream>>>((const int4*)src, (const int4*)dst,
                                     sc, bsum, tmp, NE / 4);
    k_fill512<<<NCB, 1024, 0, stream>>>(tmp, sc, bsum, csr, degi, offs, dis, NN, NE);

    const int PGRID = (NN + 63) / 64;  // 1563: 64 nodes/block, 4 lanes/node

    // Layer 1: transform-first GEMM (128->32) -> fp8 H1; pull -> fp8 H2
    k_gemm1<<<(NN + 31) / 32, 256, 0, stream>>>(x, W1, dis, H1, NN);
    k_pull2<<<PGRID, 256, 0, stream>>>((const uint2*)H1, offs, degi, csr, dis, b1,
                                       (uint2*)H2, NN);

    // Layer 2: pull(32 fp8) + fused gemm 32->48 -> fp8 H3 (PLANAR)
    k_pullmm32<<<PGRID, 256, 0, stream>>>((const uint2*)H2, offs, degi, csr, dis,
                                          W2, b2, H3, NN);

    // Layer 3: XCD-sliced planar pull -> fp16 G planes; then GEMM 48->64
    k_pull3<<<T3GRID, 256, 0, stream>>>(H3, offs, degi, csr, dis, G0, G1, G2, NN);
    k_mm48<<<PGRID, 256, 0, stream>>>(G0, G1, G2, W3, b3, A3, NN);

    // Fused bounds + pool + head
    k_poolhead<<<NG, 256, 0, stream>>>(A3, batch, f1w, f1b, f2w, f2b, out, NN, NG);
}

// Round 14
// 319.175 us; speedup vs baseline: 1.2024x; 1.2024x over previous
//
#include <hip/hip_runtime.h>
#include <hip/hip_fp16.h>

static constexpr int NN = 100000;
static constexpr int NE = 3200000;
static constexpr int NG = 512;
static constexpr int NCB = 196;                       // coarse bins: 512 nodes (dst>>9)
static constexpr int CHK = 8192;
static constexpr int NCH = (NE + CHK - 1) / CHK;      // 391 chunks
static constexpr int NCNT = NCB * NCH;                // 76636 count cells
static constexpr int SCAN_BLK = 2048;
static constexpr int NSB = (NCNT + SCAN_BLK - 1) / SCAN_BLK;  // 38
static constexpr int CAPE = 24576;                    // 96KB LDS edge buffer/bin

// Session ledger:
//  R5: NT scattered stores -> 9x write amp. R6: NT csr loads bypass L1 -> +46%.
//  R7: W from global -> +38%. R8: low-LDS small blocks -> worse. R10: LPT null.
//  R13: XCD-planar slicing: FETCH 100->38MB CONFIRMED but dur 53->88 (slice
//  imbalance + split overhead) -> dur does NOT track HBM miss count. Invariant
//  across R2/R4/R13 is gather REQUEST COUNT -> R14 halves it for layers 1-2:
//  parity-split 4-lane groups, uint4 (2 req/edge vs 4), same grid/occupancy,
//  cross-parity shfl_xor reduction at loop end. R11 base (327us) elsewhere.
typedef float f32x2 __attribute__((ext_vector_type(2)));

__device__ __forceinline__ void set2_fp8x4(unsigned v, f32x2* a) {
    a[0] = __builtin_amdgcn_cvt_pk_f32_fp8((int)v, false);
    a[1] = __builtin_amdgcn_cvt_pk_f32_fp8((int)v, true);
}
__device__ __forceinline__ void acc2_fp8x4(unsigned v, f32x2* a) {
    a[0] += __builtin_amdgcn_cvt_pk_f32_fp8((int)v, false);   // v_pk_add_f32
    a[1] += __builtin_amdgcn_cvt_pk_f32_fp8((int)v, true);
}
__device__ __forceinline__ unsigned pack_fp8x4(float a, float b, float c, float d) {
    int p = __builtin_amdgcn_cvt_pk_fp8_f32(a, b, 0, false);
    p = __builtin_amdgcn_cvt_pk_fp8_f32(c, d, p, true);
    return (unsigned)p;
}
__device__ __forceinline__ unsigned pkh2(float a, float b) {
    __half2 h = __floats2half2_rn(a, b);
    return *(unsigned*)&h;
}

// ---- per-chunk coarse histogram (int4 dst stream): cntC[bin*NCH + chunk] ---
__global__ __launch_bounds__(256) void k_histC(const int4* __restrict__ dst4,
                                               int* __restrict__ cntC, int e4) {
    __shared__ int h[NCB];
    for (int i = threadIdx.x; i < NCB; i += 256) h[i] = 0;
    __syncthreads();
    const int s4 = blockIdx.x * (CHK / 4), e4end = min(s4 + CHK / 4, e4);
    for (int i = s4 + threadIdx.x; i < e4end; i += 256) {
        int4 d = dst4[i];
        atomicAdd(&h[d.x >> 9], 1);
        atomicAdd(&h[d.y >> 9], 1);
        atomicAdd(&h[d.z >> 9], 1);
        atomicAdd(&h[d.w >> 9], 1);
    }
    __syncthreads();
    for (int i = threadIdx.x; i < NCB; i += 256)
        cntC[(size_t)i * NCH + blockIdx.x] = h[i];
}

// ---- 2-kernel exclusive scan (block-local + bsum scan; add folded later) ---
__global__ __launch_bounds__(256) void k_scanA(const int* __restrict__ in,
                                               int* __restrict__ out,
                                               int* __restrict__ bsum, int n) {
    __shared__ int s[256];
    const int tid = threadIdx.x;
    const int base = blockIdx.x * SCAN_BLK + tid * 8;
    int v[8], t = 0;
#pragma unroll
    for (int c = 0; c < 8; c++) {
        int idx = base + c;
        v[c] = (idx < n) ? in[idx] : 0;
        t += v[c];
    }
    s[tid] = t;
    __syncthreads();
    for (int off = 1; off < 256; off <<= 1) {
        int x = (tid >= off) ? s[tid - off] : 0;
        __syncthreads();
        s[tid] += x;
        __syncthreads();
    }
    if (tid == 255) bsum[blockIdx.x] = s[255];
    int run = s[tid] - t;
#pragma unroll
    for (int c = 0; c < 8; c++) {
        int idx = base + c;
        if (idx < n) out[idx] = run;
        run += v[c];
    }
}

__global__ __launch_bounds__(256) void k_scanB(int* __restrict__ bsum, int nb) {
    __shared__ int s[256];
    const int tid = threadIdx.x;
    int v = (tid < nb) ? bsum[tid] : 0;
    s[tid] = v;
    __syncthreads();
    for (int off = 1; off < 256; off <<= 1) {
        int x = (tid >= off) ? s[tid - off] : 0;
        __syncthreads();
        s[tid] += x;
        __syncthreads();
    }
    if (tid < nb) bsum[tid] = s[tid] - v;
}

// ---- coarse scatter (int4 streams): tmp[pos] = (dst&511)<<17 | src ---------
__global__ __launch_bounds__(256) void k_scatC(const int4* __restrict__ src4,
                                               const int4* __restrict__ dst4,
                                               const int* __restrict__ sc,
                                               const int* __restrict__ bsum,
                                               unsigned* __restrict__ tmp, int e4) {
    __shared__ int cur[NCB];
    for (int i = threadIdx.x; i < NCB; i += 256) {
        size_t idx = (size_t)i * NCH + blockIdx.x;
        cur[i] = sc[idx] + bsum[idx >> 11];
    }
    __syncthreads();
    const int s4 = blockIdx.x * (CHK / 4), e4end = min(s4 + CHK / 4, e4);
    for (int i = s4 + threadIdx.x; i < e4end; i += 256) {
        int4 d = dst4[i];
        int4 sv = src4[i];
        int p0 = atomicAdd(&cur[d.x >> 9], 1);
        tmp[p0] = ((unsigned)(d.x & 511) << 17) | (unsigned)sv.x;
        int p1 = atomicAdd(&cur[d.y >> 9], 1);
        tmp[p1] = ((unsigned)(d.y & 511) << 17) | (unsigned)sv.y;
        int p2 = atomicAdd(&cur[d.z >> 9], 1);
        tmp[p2] = ((unsigned)(d.z & 511) << 17) | (unsigned)sv.z;
        int p3 = atomicAdd(&cur[d.w >> 9], 1);
        tmp[p3] = ((unsigned)(d.w & 511) << 17) | (unsigned)sv.w;
    }
}

// ---- per-bin (512 nodes): single global read into LDS; count/scan/scatter --
__global__ __launch_bounds__(1024) void k_fill512(const unsigned* __restrict__ tmp,
                                                  const int* __restrict__ sc,
                                                  const int* __restrict__ bsum,
                                                  int* __restrict__ csr,
                                                  int* __restrict__ degi,
                                                  int* __restrict__ offs,
                                                  float* __restrict__ dis,
                                                  int n, int etotal) {
    __shared__ unsigned eL[CAPE];   // 96 KB edge cache
    __shared__ int cnt[512];
    __shared__ int s[512];
    __shared__ int cur[512];
    const int b = blockIdx.x, tid = threadIdx.x;
    if (tid < 512) cnt[tid] = 0;
    size_t i0 = (size_t)b * NCH;
    const int e0 = sc[i0] + bsum[i0 >> 11];
    int e1 = etotal;
    if (b + 1 < NCB) {
        size_t i1 = (size_t)(b + 1) * NCH;
        e1 = sc[i1] + bsum[i1 >> 11];
    }
    const int m = e1 - e0;
    const bool fits = (m <= CAPE);
    __syncthreads();
    if (fits) {
        for (int i = tid; i < m; i += 1024) {     // one global pass: load+count
            unsigned pk = tmp[e0 + i];
            eL[i] = pk;
            atomicAdd(&cnt[pk >> 17], 1);
        }
    } else {
        for (int e = e0 + tid; e < e1; e += 1024)
            atomicAdd(&cnt[tmp[e] >> 17], 1);
    }
    __syncthreads();
    int v = 0;
    if (tid < 512) { v = cnt[tid]; s[tid] = v; }
    __syncthreads();
    for (int off = 1; off < 512; off <<= 1) {
        int x = 0;
        if (tid < 512 && tid >= off) x = s[tid - off];
        __syncthreads();
        if (tid < 512) s[tid] += x;
        __syncthreads();
    }
    if (tid < 512) {
        int c = e0 + s[tid] - v;   // exclusive prefix within bin window
        cur[tid] = c;
        int node = b * 512 + tid;
        if (node < n) {
            degi[node] = v;
            offs[node] = c;
            dis[node] = rsqrtf((float)v + 1.0f);
        }
    }
    __syncthreads();
    if (fits) {
        for (int i = tid; i < m; i += 1024) {
            unsigned pk = eL[i];
            int p = atomicAdd(&cur[pk >> 17], 1);
            csr[p] = (int)(pk & 0x1FFFFu);
        }
    } else {
        for (int e = e0 + tid; e < e1; e += 1024) {
            unsigned pk = tmp[e];
            int p = atomicAdd(&cur[pk >> 17], 1);
            csr[p] = (int)(pk & 0x1FFFFu);
        }
    }
}

// ---- gemm1: H1' = fp8((x @ W1) * dis[row])  (128 -> 32) --------------------
__global__ __launch_bounds__(256) void k_gemm1(const float* __restrict__ X,
                                               const float* __restrict__ W,
                                               const float* __restrict__ dis,
                                               unsigned* __restrict__ H, int n) {
    constexpr int IN = 128, ROWS = 32;
    __shared__ float sW[IN * 32];
    __shared__ float sX[ROWS][IN];
    const int tid = threadIdx.x;
    for (int i = tid; i < IN * 32; i += 256) sW[i] = W[i];
    const int row0 = blockIdx.x * ROWS;
    const float4* X4 = (const float4*)X;
    for (int i = tid; i < ROWS * 32; i += 256) {
        int r = row0 + (i >> 5);
        float4 v = make_float4(0.f, 0.f, 0.f, 0.f);
        if (r < n) v = X4[(size_t)r * 32 + (i & 31)];
        ((float4*)&sX[i >> 5][0])[i & 31] = v;
    }
    __syncthreads();
    const int lr = tid >> 3;        // local row
    const int cg = tid & 7;         // col group (4 cols)
    const int gr = row0 + lr;
    float acc[4] = {0.f, 0.f, 0.f, 0.f};
#pragma unroll 8
    for (int k = 0; k < IN; k++) {
        float xv = sX[lr][k];
#pragma unroll
        for (int c = 0; c < 4; c++)
            acc[c] = fmaf(xv, sW[k * 32 + 4 * cg + c], acc[c]);
    }
    if (gr < n) {
        float dd = dis[gr];
        H[(size_t)gr * 8 + cg] =
            pack_fp8x4(acc[0] * dd, acc[1] * dd, acc[2] * dd, acc[3] * dd);
    }
}

// ---- layer-1 pull (32 fp8): parity-split 4-lane groups, uint4 gathers ------
// lane (h = tid&1, p = (tid>>1)&1): loads half h of edges with parity p.
// 2 requests/edge (was 4). Cross-parity shfl_xor(2) reduction at loop end.
__global__ __launch_bounds__(256) void k_pull2(
        const uint4* __restrict__ Hp, const int* __restrict__ offs,
        const int* __restrict__ degi, const int* __restrict__ csr,
        const float* __restrict__ dis, const float* __restrict__ b,
        uint4* __restrict__ A, int n) {
    const int group = threadIdx.x >> 2;
    const int h = threadIdx.x & 1;
    const int p = (threadIdx.x >> 1) & 1;
    const int d = blockIdx.x * 64 + group;
    if (d >= n) return;
    f32x2 acc[8];
    if (p == 0) {                       // self-loop counted once (parity 0)
        uint4 sv = Hp[(size_t)d * 2 + h];
        set2_fp8x4(sv.x, acc);     set2_fp8x4(sv.y, acc + 2);
        set2_fp8x4(sv.z, acc + 4); set2_fp8x4(sv.w, acc + 6);
    } else {
#pragma unroll
        for (int c = 0; c < 8; c++) { acc[c].x = 0.f; acc[c].y = 0.f; }
    }
    const int e0 = offs[d];
    const int end = e0 + degi[d];
    for (int e = e0 + p; e < end; e += 8) {   // this lane: e, e+2, e+4, e+6
        uint4 v[4];
#pragma unroll
        for (int i = 0; i < 4; i++) {
            int ee = e + 2 * i;
            int idx = csr[min(ee, NE - 1)];
            uint4 t = Hp[(size_t)idx * 2 + h];
            if (ee >= end) { t.x = 0u; t.y = 0u; t.z = 0u; t.w = 0u; }
            v[i] = t;
        }
#pragma unroll
        for (int i = 0; i < 4; i++) {
            acc2_fp8x4(v[i].x, acc);     acc2_fp8x4(v[i].y, acc + 2);
            acc2_fp8x4(v[i].z, acc + 4); acc2_fp8x4(v[i].w, acc + 6);
        }
    }
    // combine parities: lanes (h,p) and (h,p^1) differ in bit 1
#pragma unroll
    for (int c = 0; c < 8; c++) {
        acc[c].x += __shfl_xor(acc[c].x, 2);
        acc[c].y += __shfl_xor(acc[c].y, 2);
    }
    if (p == 0) {
        const float dd = dis[d];
        float r[16];
#pragma unroll
        for (int c = 0; c < 8; c++) {
            r[2 * c]     = fmaxf(fmaf(acc[c].x, dd, b[16 * h + 2 * c]), 0.f) * dd;
            r[2 * c + 1] = fmaxf(fmaf(acc[c].y, dd, b[16 * h + 2 * c + 1]), 0.f) * dd;
        }
        A[(size_t)d * 2 + h] =
            make_uint4(pack_fp8x4(r[0],  r[1],  r[2],  r[3]),
                       pack_fp8x4(r[4],  r[5],  r[6],  r[7]),
                       pack_fp8x4(r[8],  r[9],  r[10], r[11]),
                       pack_fp8x4(r[12], r[13], r[14], r[15]));
    }
}

// ---- layer-2: parity-split pull(32 fp8) + fused gemm 32->48 -> fp8 48B rows
// Gather identical to k_pull2; epilogue identical to R11 (64 nodes/256 thr).
__global__ __launch_bounds__(256) void k_pullmm32(
        const uint4* __restrict__ Hp, const int* __restrict__ offs,
        const int* __restrict__ degi, const int* __restrict__ csr,
        const float* __restrict__ dis, const float* __restrict__ W,
        const float* __restrict__ b, unsigned* __restrict__ A, int n) {
    __shared__ float sW[32 * 48];    // 6 KB
    __shared__ float rows[64][33];   // 8.25 KB
    for (int i = threadIdx.x; i < 32 * 48; i += 256) sW[i] = W[i];
    const int group = threadIdx.x >> 2;
    const int h = threadIdx.x & 1;
    const int p = (threadIdx.x >> 1) & 1;
    const int d = blockIdx.x * 64 + group;
    if (d < n) {
        f32x2 acc[8];
        if (p == 0) {
            uint4 sv = Hp[(size_t)d * 2 + h];
            set2_fp8x4(sv.x, acc);     set2_fp8x4(sv.y, acc + 2);
            set2_fp8x4(sv.z, acc + 4); set2_fp8x4(sv.w, acc + 6);
        } else {
#pragma unroll
            for (int c = 0; c < 8; c++) { acc[c].x = 0.f; acc[c].y = 0.f; }
        }
        const int e0 = offs[d];
        const int end = e0 + degi[d];
        for (int e = e0 + p; e < end; e += 8) {
            uint4 v[4];
#pragma unroll
            for (int i = 0; i < 4; i++) {
                int ee = e + 2 * i;
                int idx = csr[min(ee, NE - 1)];
                uint4 t = Hp[(size_t)idx * 2 + h];
                if (ee >= end) { t.x = 0u; t.y = 0u; t.z = 0u; t.w = 0u; }
                v[i] = t;
            }
#pragma unroll
            for (int i = 0; i < 4; i++) {
                acc2_fp8x4(v[i].x, acc);     acc2_fp8x4(v[i].y, acc + 2);
                acc2_fp8x4(v[i].z, acc + 4); acc2_fp8x4(v[i].w, acc + 6);
            }
        }
#pragma unroll
        for (int c = 0; c < 8; c++) {
            acc[c].x += __shfl_xor(acc[c].x, 2);
            acc[c].y += __shfl_xor(acc[c].y, 2);
        }
        if (p == 0) {
            const float dd = dis[d];
#pragma unroll
            for (int c = 0; c < 8; c++) {
                rows[group][16 * h + 2 * c]     = acc[c].x * dd;
                rows[group][16 * h + 2 * c + 1] = acc[c].y * dd;
            }
        }
    }
    __syncthreads();
    const int row0 = blockIdx.x * 64;
    const int nl = threadIdx.x & 63, cgb = threadIdx.x >> 6;  // row, col-block
    const int gr = row0 + nl;
    if (gr < n) {
        const float4* sW4 = (const float4*)sW;
        float s[3][4];
#pragma unroll
        for (int o = 0; o < 3; o++)
#pragma unroll
            for (int c = 0; c < 4; c++) s[o][c] = b[12 * cgb + 4 * o + c];
#pragma unroll 8
        for (int k = 0; k < 32; k++) {
            float rv = rows[nl][k];
#pragma unroll
            for (int o = 0; o < 3; o++) {
                float4 w = sW4[k * 12 + cgb * 3 + o];   // wave-uniform broadcast
                s[o][0] = fmaf(rv, w.x, s[o][0]);
                s[o][1] = fmaf(rv, w.y, s[o][1]);
                s[o][2] = fmaf(rv, w.z, s[o][2]);
                s[o][3] = fmaf(rv, w.w, s[o][3]);
            }
        }
        const float dd2 = dis[gr];
#pragma unroll
        for (int o = 0; o < 3; o++) {
            float r0 = fmaxf(s[o][0], 0.f) * dd2;
            float r1 = fmaxf(s[o][1], 0.f) * dd2;
            float r2 = fmaxf(s[o][2], 0.f) * dd2;
            float r3 = fmaxf(s[o][3], 0.f) * dd2;
            A[(size_t)gr * 12 + cgb * 3 + o] = pack_fp8x4(r0, r1, r2, r3);
        }
    }
}

// ---- layer-3: pull(48 fp8, 48B rows) + fused gemm 48->64 -> A3 fp16 --------
// R11 structure frozen: 64 nodes/256 thr, 3 active lanes x uint4, sW in LDS
__global__ __launch_bounds__(256) void k_pullmm48(
        const uint4* __restrict__ Hp,   // 3 x uint4 per row (48B)
        const int* __restrict__ offs,
        const int* __restrict__ degi, const int* __restrict__ csr,
        const float* __restrict__ dis, const float* __restrict__ W,
        const float* __restrict__ b, __half* __restrict__ A, int n) {
    __shared__ float sW[48 * 64];   // 12 KB
    __shared__ float rows[64][49];  // 12.25 KB
    for (int i = threadIdx.x; i < 48 * 64; i += 256) sW[i] = W[i];
    const int group = threadIdx.x >> 2, j0 = threadIdx.x & 3;
    const int d = blockIdx.x * 64 + group;
    if (d < n && j0 < 3) {          // lane 3 idles through the gather phase
        f32x2 acc[8];
        uint4 sv = Hp[(size_t)d * 3 + j0];
        set2_fp8x4(sv.x, acc);     set2_fp8x4(sv.y, acc + 2);
        set2_fp8x4(sv.z, acc + 4); set2_fp8x4(sv.w, acc + 6);
        int e = offs[d];
        const int end = e + degi[d];
        for (; e < end; e += 8) {
            uint4 v[8];
#pragma unroll
            for (int i = 0; i < 8; i++) {
                int ee = e + i;
                int idx = csr[min(ee, NE - 1)];
                uint4 t = Hp[(size_t)idx * 3 + j0];
                if (ee >= end) { t.x = 0u; t.y = 0u; t.z = 0u; t.w = 0u; }
                v[i] = t;
            }
#pragma unroll
            for (int i = 0; i < 8; i++) {
                acc2_fp8x4(v[i].x, acc);     acc2_fp8x4(v[i].y, acc + 2);
                acc2_fp8x4(v[i].z, acc + 4); acc2_fp8x4(v[i].w, acc + 6);
            }
        }
        const float dd = dis[d];
#pragma unroll
        for (int c = 0; c < 8; c++) {
            rows[group][16 * j0 + 2 * c]     = acc[c].x * dd;
            rows[group][16 * j0 + 2 * c + 1] = acc[c].y * dd;
        }
    }
    __syncthreads();
    const int row0 = blockIdx.x * 64;
    const int nl = threadIdx.x & 63, cgb = threadIdx.x >> 6;  // row, 16-col block
    const int gr = row0 + nl;
    if (gr < n) {
        const float4* sW4 = (const float4*)sW;
        float s[4][4];
#pragma unroll
        for (int o = 0; o < 4; o++)
#pragma unroll
            for (int c = 0; c < 4; c++) s[o][c] = b[16 * cgb + 4 * o + c];
#pragma unroll 8
        for (int k = 0; k < 48; k++) {
            float rv = rows[nl][k];
#pragma unroll
            for (int o = 0; o < 4; o++) {
                float4 w = sW4[k * 16 + cgb * 4 + o];   // wave-uniform broadcast
                s[o][0] = fmaf(rv, w.x, s[o][0]);
                s[o][1] = fmaf(rv, w.y, s[o][1]);
                s[o][2] = fmaf(rv, w.z, s[o][2]);
                s[o][3] = fmaf(rv, w.w, s[o][3]);
            }
        }
        uint4 q0, q1;
        q0.x = pkh2(s[0][0], s[0][1]); q0.y = pkh2(s[0][2], s[0][3]);
        q0.z = pkh2(s[1][0], s[1][1]); q0.w = pkh2(s[1][2], s[1][3]);
        q1.x = pkh2(s[2][0], s[2][1]); q1.y = pkh2(s[2][2], s[2][3]);
        q1.z = pkh2(s[3][0], s[3][1]); q1.w = pkh2(s[3][2], s[3][3]);
        ((uint4*)A)[(size_t)gr * 8 + cgb * 2]     = q0;
        ((uint4*)A)[(size_t)gr * 8 + cgb * 2 + 1] = q1;
    }
}

// ---- fused: bounds + mean-pool (32 rows in flight) + MLP head + softmax ----
__global__ __launch_bounds__(256) void k_poolhead(
        const __half* __restrict__ A3, const int* __restrict__ batch,
        const float* __restrict__ f1w, const float* __restrict__ f1b,
        const float* __restrict__ f2w, const float* __restrict__ f2b,
        float* __restrict__ out, int n, int ngr) {
    const int g = blockIdx.x;
    __shared__ int sb[2];
    if (threadIdx.x < 2) {
        int target = g + threadIdx.x;
        int lo = 0, hi = n;
        while (lo < hi) {
            int mid = (lo + hi) >> 1;
            if (batch[mid] < target) lo = mid + 1; else hi = mid;
        }
        sb[threadIdx.x] = lo;
    }
    __syncthreads();
    const int s = sb[0], e = sb[1];
    const int cg8 = threadIdx.x & 7;      // col-group (8 halves)
    const int rr  = threadIdx.x >> 3;     // 0..31 row offset
    float sum[8] = {0.f, 0.f, 0.f, 0.f, 0.f, 0.f, 0.f, 0.f};
    for (int node = s + rr; node < e; node += 32) {
        uint4 v = *(const uint4*)(A3 + (size_t)node * 64 + cg8 * 8);
        unsigned w[4] = {v.x, v.y, v.z, v.w};
#pragma unroll
        for (int h = 0; h < 4; h++) {
            __half2 h2 = *(__half2*)&w[h];
            float2 f = __half22float2(h2);
            sum[2 * h]     += fmaxf(f.x, 0.f);
            sum[2 * h + 1] += fmaxf(f.y, 0.f);
        }
    }
    __shared__ float red[32][64];
#pragma unroll
    for (int h = 0; h < 8; h++) red[rr][cg8 * 8 + h] = sum[h];
    __syncthreads();
    __shared__ float p[64], z[32], lg[16];
    const int t = threadIdx.x;
    if (t < 64) {
        float acc = 0.f;
#pragma unroll 8
        for (int r = 0; r < 32; r++) acc += red[r][t];
        p[t] = acc / fmaxf((float)(e - s), 1.f);
    }
    __syncthreads();
    if (t < 32) {
        float acc = f1b[t];
        for (int k = 0; k < 64; k++) acc = fmaf(p[k], f1w[k * 32 + t], acc);
        z[t] = fmaxf(acc, 0.f);
    }
    __syncthreads();
    if (t < 16) {
        float acc = f2b[t];
        for (int k = 0; k < 32; k++) acc = fmaf(z[k], f2w[k * 16 + t], acc);
        lg[t] = acc;
    }
    __syncthreads();
    if (t < 16) {
        float m = lg[0];
        for (int i = 1; i < 16; i++) m = fmaxf(m, lg[i]);
        float sden = 0.f;
        for (int i = 0; i < 16; i++) sden += expf(lg[i] - m);
        out[g * 16 + t] = expf(lg[t] - m) / sden;
    }
}

extern "C" void kernel_launch(void* const* d_in, const int* in_sizes, int n_in,
                              void* d_out, int out_size, void* d_ws, size_t ws_size,
                              hipStream_t stream) {
    (void)in_sizes; (void)n_in; (void)out_size; (void)ws_size;
    const float* x     = (const float*)d_in[0];
    const int*   ei    = (const int*)d_in[1];
    const int*   batch = (const int*)d_in[2];
    const float* W1 = (const float*)d_in[3];
    const float* b1 = (const float*)d_in[4];
    const float* W2 = (const float*)d_in[5];  const float* b2 = (const float*)d_in[6];
    const float* W3 = (const float*)d_in[7];  const float* b3 = (const float*)d_in[8];
    const float* f1w = (const float*)d_in[9]; const float* f1b = (const float*)d_in[10];
    const float* f2w = (const float*)d_in[11];const float* f2b = (const float*)d_in[12];
    float* out = (float*)d_out;

    const int* src = ei;
    const int* dst = ei + NE;

    // Workspace (~40 MB):
    //   tmp uint[NE] (12.8MB)  aliased with  A3 fp16[NN*64] (12.8MB)
    //   H1 fp8[NN*32] (3.2MB), H2 fp8[NN*32] (3.2MB), H3 fp8[NN*48] (4.8MB)
    float* ws = (float*)d_ws;
    size_t o = 0;
    float* dis    = ws + o; o += NN;
    int*   degi   = (int*)(ws + o); o += NN;
    int*   offs   = (int*)(ws + o); o += NN;
    int*   cntC   = (int*)(ws + o); o += 76640;       // NCNT padded to /16
    int*   sc     = (int*)(ws + o); o += 76640;
    int*   bsum   = (int*)(ws + o); o += 48;
    int*   csr    = (int*)(ws + o); o += NE;
    unsigned* TA  = (unsigned*)(ws + o); o += NE;     // tmp | A3
    unsigned* H1  = (unsigned*)(ws + o); o += NN * 8;
    unsigned* H2  = (unsigned*)(ws + o); o += NN * 8;
    unsigned* H3  = (unsigned*)(ws + o); o += NN * 12;  // 48B rows, 16B aligned

    unsigned* tmp = (unsigned*)TA;
    __half*   A3  = (__half*)TA;

    // CSR build: coarse counting sort (196 bins x 512 nodes) + in-LDS sub-sort
    k_histC<<<NCH, 256, 0, stream>>>((const int4*)dst, cntC, NE / 4);
    k_scanA<<<NSB, 256, 0, stream>>>(cntC, sc, bsum, NCNT);
    k_scanB<<<1, 256, 0, stream>>>(bsum, NSB);
    k_scatC<<<NCH, 256, 0, stream>>>((const int4*)src, (const int4*)dst,
                                     sc, bsum, tmp, NE / 4);
    k_fill512<<<NCB, 1024, 0, stream>>>(tmp, sc, bsum, csr, degi, offs, dis, NN, NE);

    const int PGRID = (NN + 63) / 64;  // 1563: 64 nodes/block, 4 lanes/node

    // Layer 1: transform-first GEMM (128->32) -> fp8 H1; pull -> fp8 H2
    k_gemm1<<<(NN + 31) / 32, 256, 0, stream>>>(x, W1, dis, H1, NN);
    k_pull2<<<PGRID, 256, 0, stream>>>((const uint4*)H1, offs, degi, csr, dis, b1,
                                       (uint4*)H2, NN);

    // Layer 2: pull(32 fp8) + fused gemm 32->48 -> fp8 H3 (48B rows)
    k_pullmm32<<<PGRID, 256, 0, stream>>>((const uint4*)H2, offs, degi, csr, dis,
                                          W2, b2, H3, NN);

    // Layer 3: pull(48 fp8) + fused gemm 48->64 -> A3 fp16
    k_pullmm48<<<PGRID, 256, 0, stream>>>(
        (const uint4*)H3, offs, degi, csr, dis, W3, b3, A3, NN);

    // Fused bounds + pool + head
    k_poolhead<<<NG, 256, 0, stream>>>(A3, batch, f1w, f1b, f2w, f2b, out, NN, NG);
}

// Round 15
// 318.025 us; speedup vs baseline: 1.2067x; 1.0036x over previous
//
#include <hip/hip_runtime.h>
#include <hip/hip_fp16.h>

static constexpr int NN = 100000;
static constexpr int NE = 3200000;
static constexpr int NG = 512;
static constexpr int NCB = 196;                       // coarse bins: 512 nodes (dst>>9)
static constexpr int CHK = 8192;
static constexpr int NCH = (NE + CHK - 1) / CHK;      // 391 chunks
static constexpr int NCNT = NCB * NCH;                // 76636 count cells
static constexpr int SCAN_BLK = 2048;
static constexpr int NSB = (NCNT + SCAN_BLK - 1) / SCAN_BLK;  // 38
static constexpr int CAPE = 24576;                    // 96KB LDS edge buffer/bin

// Session ledger:
//  R5: NT scattered stores -> 9x write amp. R6: NT csr loads bypass L1 -> +46%.
//  R7: W from global -> +38%. R8: low-LDS small blocks -> worse. R10: LPT null.
//  R13: XCD-planar: FETCH 100->38MB confirmed, dur 53->88 -> dur tracks gather
//  REQUEST count, not HBM bytes. R14 (319us): parity-split layers 1-2 (2 req/
//  edge) -8us, confirming request model. R15: cut VMEM instruction issue at
//  constant traffic: csr loads vectorized 8x4B -> 2x dwordx4 (align-4) in all
//  pulls (csr padded +8 zeros); fill512 load pass uint4-vectorized.
typedef float f32x2 __attribute__((ext_vector_type(2)));

struct u4u { unsigned x, y, z, w; } __attribute__((aligned(4)));
__device__ __forceinline__ u4u ldg4u(const int* p) { return *(const u4u*)p; }

__device__ __forceinline__ void set2_fp8x4(unsigned v, f32x2* a) {
    a[0] = __builtin_amdgcn_cvt_pk_f32_fp8((int)v, false);
    a[1] = __builtin_amdgcn_cvt_pk_f32_fp8((int)v, true);
}
__device__ __forceinline__ void acc2_fp8x4(unsigned v, f32x2* a) {
    a[0] += __builtin_amdgcn_cvt_pk_f32_fp8((int)v, false);   // v_pk_add_f32
    a[1] += __builtin_amdgcn_cvt_pk_f32_fp8((int)v, true);
}
__device__ __forceinline__ unsigned pack_fp8x4(float a, float b, float c, float d) {
    int p = __builtin_amdgcn_cvt_pk_fp8_f32(a, b, 0, false);
    p = __builtin_amdgcn_cvt_pk_fp8_f32(c, d, p, true);
    return (unsigned)p;
}
__device__ __forceinline__ unsigned pkh2(float a, float b) {
    __half2 h = __floats2half2_rn(a, b);
    return *(unsigned*)&h;
}

// ---- per-chunk coarse histogram (int4 dst stream): cntC[bin*NCH + chunk] ---
__global__ __launch_bounds__(256) void k_histC(const int4* __restrict__ dst4,
                                               int* __restrict__ cntC, int e4) {
    __shared__ int h[NCB];
    for (int i = threadIdx.x; i < NCB; i += 256) h[i] = 0;
    __syncthreads();
    const int s4 = blockIdx.x * (CHK / 4), e4end = min(s4 + CHK / 4, e4);
    for (int i = s4 + threadIdx.x; i < e4end; i += 256) {
        int4 d = dst4[i];
        atomicAdd(&h[d.x >> 9], 1);
        atomicAdd(&h[d.y >> 9], 1);
        atomicAdd(&h[d.z >> 9], 1);
        atomicAdd(&h[d.w >> 9], 1);
    }
    __syncthreads();
    for (int i = threadIdx.x; i < NCB; i += 256)
        cntC[(size_t)i * NCH + blockIdx.x] = h[i];
}

// ---- 2-kernel exclusive scan (block-local + bsum scan; add folded later) ---
__global__ __launch_bounds__(256) void k_scanA(const int* __restrict__ in,
                                               int* __restrict__ out,
                                               int* __restrict__ bsum, int n) {
    __shared__ int s[256];
    const int tid = threadIdx.x;
    const int base = blockIdx.x * SCAN_BLK + tid * 8;
    int v[8], t = 0;
#pragma unroll
    for (int c = 0; c < 8; c++) {
        int idx = base + c;
        v[c] = (idx < n) ? in[idx] : 0;
        t += v[c];
    }
    s[tid] = t;
    __syncthreads();
    for (int off = 1; off < 256; off <<= 1) {
        int x = (tid >= off) ? s[tid - off] : 0;
        __syncthreads();
        s[tid] += x;
        __syncthreads();
    }
    if (tid == 255) bsum[blockIdx.x] = s[255];
    int run = s[tid] - t;
#pragma unroll
    for (int c = 0; c < 8; c++) {
        int idx = base + c;
        if (idx < n) out[idx] = run;
        run += v[c];
    }
}

__global__ __launch_bounds__(256) void k_scanB(int* __restrict__ bsum, int nb) {
    __shared__ int s[256];
    const int tid = threadIdx.x;
    int v = (tid < nb) ? bsum[tid] : 0;
    s[tid] = v;
    __syncthreads();
    for (int off = 1; off < 256; off <<= 1) {
        int x = (tid >= off) ? s[tid - off] : 0;
        __syncthreads();
        s[tid] += x;
        __syncthreads();
    }
    if (tid < nb) bsum[tid] = s[tid] - v;
}

// ---- coarse scatter (int4 streams): tmp[pos] = (dst&511)<<17 | src ---------
__global__ __launch_bounds__(256) void k_scatC(const int4* __restrict__ src4,
                                               const int4* __restrict__ dst4,
                                               const int* __restrict__ sc,
                                               const int* __restrict__ bsum,
                                               unsigned* __restrict__ tmp, int e4) {
    __shared__ int cur[NCB];
    for (int i = threadIdx.x; i < NCB; i += 256) {
        size_t idx = (size_t)i * NCH + blockIdx.x;
        cur[i] = sc[idx] + bsum[idx >> 11];
    }
    __syncthreads();
    const int s4 = blockIdx.x * (CHK / 4), e4end = min(s4 + CHK / 4, e4);
    for (int i = s4 + threadIdx.x; i < e4end; i += 256) {
        int4 d = dst4[i];
        int4 sv = src4[i];
        int p0 = atomicAdd(&cur[d.x >> 9], 1);
        tmp[p0] = ((unsigned)(d.x & 511) << 17) | (unsigned)sv.x;
        int p1 = atomicAdd(&cur[d.y >> 9], 1);
        tmp[p1] = ((unsigned)(d.y & 511) << 17) | (unsigned)sv.y;
        int p2 = atomicAdd(&cur[d.z >> 9], 1);
        tmp[p2] = ((unsigned)(d.z & 511) << 17) | (unsigned)sv.z;
        int p3 = atomicAdd(&cur[d.w >> 9], 1);
        tmp[p3] = ((unsigned)(d.w & 511) << 17) | (unsigned)sv.w;
    }
}

// ---- per-bin (512 nodes): single global read into LDS; count/scan/scatter --
__global__ __launch_bounds__(1024) void k_fill512(const unsigned* __restrict__ tmp,
                                                  const int* __restrict__ sc,
                                                  const int* __restrict__ bsum,
                                                  int* __restrict__ csr,
                                                  int* __restrict__ degi,
                                                  int* __restrict__ offs,
                                                  float* __restrict__ dis,
                                                  int n, int etotal) {
    __shared__ unsigned eL[CAPE];   // 96 KB edge cache
    __shared__ int cnt[512];
    __shared__ int s[512];
    __shared__ int cur[512];
    const int b = blockIdx.x, tid = threadIdx.x;
    if (tid < 512) cnt[tid] = 0;
    if (b == 0 && tid < 8) csr[etotal + tid] = 0;   // pad for vector csr loads
    size_t i0 = (size_t)b * NCH;
    const int e0 = sc[i0] + bsum[i0 >> 11];
    int e1 = etotal;
    if (b + 1 < NCB) {
        size_t i1 = (size_t)(b + 1) * NCH;
        e1 = sc[i1] + bsum[i1 >> 11];
    }
    const int m = e1 - e0;
    const bool fits = (m <= CAPE);
    __syncthreads();
    if (fits) {
        const int a0 = min(m, (int)((4 - (e0 & 3)) & 3));   // scalar head
        for (int i = tid; i < a0; i += 1024) {
            unsigned pk = tmp[e0 + i];
            eL[i] = pk;
            atomicAdd(&cnt[pk >> 17], 1);
        }
        const int mv = (m - a0) >> 2;                       // uint4 body
        const uint4* tv = (const uint4*)(tmp + e0 + a0);
        for (int k = tid; k < mv; k += 1024) {
            uint4 q = tv[k];
            int base = a0 + 4 * k;
            eL[base] = q.x; eL[base + 1] = q.y;
            eL[base + 2] = q.z; eL[base + 3] = q.w;
            atomicAdd(&cnt[q.x >> 17], 1);
            atomicAdd(&cnt[q.y >> 17], 1);
            atomicAdd(&cnt[q.z >> 17], 1);
            atomicAdd(&cnt[q.w >> 17], 1);
        }
        for (int i = a0 + 4 * mv + tid; i < m; i += 1024) { // scalar tail
            unsigned pk = tmp[e0 + i];
            eL[i] = pk;
            atomicAdd(&cnt[pk >> 17], 1);
        }
    } else {
        for (int e = e0 + tid; e < e1; e += 1024)
            atomicAdd(&cnt[tmp[e] >> 17], 1);
    }
    __syncthreads();
    int v = 0;
    if (tid < 512) { v = cnt[tid]; s[tid] = v; }
    __syncthreads();
    for (int off = 1; off < 512; off <<= 1) {
        int x = 0;
        if (tid < 512 && tid >= off) x = s[tid - off];
        __syncthreads();
        if (tid < 512) s[tid] += x;
        __syncthreads();
    }
    if (tid < 512) {
        int c = e0 + s[tid] - v;   // exclusive prefix within bin window
        cur[tid] = c;
        int node = b * 512 + tid;
        if (node < n) {
            degi[node] = v;
            offs[node] = c;
            dis[node] = rsqrtf((float)v + 1.0f);
        }
    }
    __syncthreads();
    if (fits) {
        for (int i = tid; i < m; i += 1024) {
            unsigned pk = eL[i];
            int p = atomicAdd(&cur[pk >> 17], 1);
            csr[p] = (int)(pk & 0x1FFFFu);
        }
    } else {
        for (int e = e0 + tid; e < e1; e += 1024) {
            unsigned pk = tmp[e];
            int p = atomicAdd(&cur[pk >> 17], 1);
            csr[p] = (int)(pk & 0x1FFFFu);
        }
    }
}

// ---- gemm1: H1' = fp8((x @ W1) * dis[row])  (128 -> 32) --------------------
__global__ __launch_bounds__(256) void k_gemm1(const float* __restrict__ X,
                                               const float* __restrict__ W,
                                               const float* __restrict__ dis,
                                               unsigned* __restrict__ H, int n) {
    constexpr int IN = 128, ROWS = 32;
    __shared__ float sW[IN * 32];
    __shared__ float sX[ROWS][IN];
    const int tid = threadIdx.x;
    for (int i = tid; i < IN * 32; i += 256) sW[i] = W[i];
    const int row0 = blockIdx.x * ROWS;
    const float4* X4 = (const float4*)X;
    for (int i = tid; i < ROWS * 32; i += 256) {
        int r = row0 + (i >> 5);
        float4 v = make_float4(0.f, 0.f, 0.f, 0.f);
        if (r < n) v = X4[(size_t)r * 32 + (i & 31)];
        ((float4*)&sX[i >> 5][0])[i & 31] = v;
    }
    __syncthreads();
    const int lr = tid >> 3;        // local row
    const int cg = tid & 7;         // col group (4 cols)
    const int gr = row0 + lr;
    float acc[4] = {0.f, 0.f, 0.f, 0.f};
#pragma unroll 8
    for (int k = 0; k < IN; k++) {
        float xv = sX[lr][k];
#pragma unroll
        for (int c = 0; c < 4; c++)
            acc[c] = fmaf(xv, sW[k * 32 + 4 * cg + c], acc[c]);
    }
    if (gr < n) {
        float dd = dis[gr];
        H[(size_t)gr * 8 + cg] =
            pack_fp8x4(acc[0] * dd, acc[1] * dd, acc[2] * dd, acc[3] * dd);
    }
}

// ---- layer-1 pull (32 fp8): parity-split, vector csr (2x dwordx4/window) ---
__global__ __launch_bounds__(256) void k_pull2(
        const uint4* __restrict__ Hp, const int* __restrict__ offs,
        const int* __restrict__ degi, const int* __restrict__ csr,
        const float* __restrict__ dis, const float* __restrict__ b,
        uint4* __restrict__ A, int n) {
    const int group = threadIdx.x >> 2;
    const int h = threadIdx.x & 1;
    const int p = (threadIdx.x >> 1) & 1;
    const int d = blockIdx.x * 64 + group;
    if (d >= n) return;
    f32x2 acc[8];
    if (p == 0) {                       // self-loop counted once (parity 0)
        uint4 sv = Hp[(size_t)d * 2 + h];
        set2_fp8x4(sv.x, acc);     set2_fp8x4(sv.y, acc + 2);
        set2_fp8x4(sv.z, acc + 4); set2_fp8x4(sv.w, acc + 6);
    } else {
#pragma unroll
        for (int c = 0; c < 8; c++) { acc[c].x = 0.f; acc[c].y = 0.f; }
    }
    const int e0 = offs[d];
    const int end = e0 + degi[d];
    for (int w = e0; w < end; w += 8) {
        u4u ca = ldg4u(csr + w);        // csr[w..w+3]   (pad keeps this safe)
        u4u cb = ldg4u(csr + w + 4);    // csr[w+4..w+7]
        unsigned cc[8] = {ca.x, ca.y, ca.z, ca.w, cb.x, cb.y, cb.z, cb.w};
        uint4 v[4];
#pragma unroll
        for (int i = 0; i < 4; i++) {
            int ee = w + p + 2 * i;
            uint4 t = Hp[(size_t)cc[p + 2 * i] * 2 + h];
            if (ee >= end) { t.x = 0u; t.y = 0u; t.z = 0u; t.w = 0u; }
            v[i] = t;
        }
#pragma unroll
        for (int i = 0; i < 4; i++) {
            acc2_fp8x4(v[i].x, acc);     acc2_fp8x4(v[i].y, acc + 2);
            acc2_fp8x4(v[i].z, acc + 4); acc2_fp8x4(v[i].w, acc + 6);
        }
    }
    // combine parities: lanes (h,p) and (h,p^1) differ in bit 1
#pragma unroll
    for (int c = 0; c < 8; c++) {
        acc[c].x += __shfl_xor(acc[c].x, 2);
        acc[c].y += __shfl_xor(acc[c].y, 2);
    }
    if (p == 0) {
        const float dd = dis[d];
        float r[16];
#pragma unroll
        for (int c = 0; c < 8; c++) {
            r[2 * c]     = fmaxf(fmaf(acc[c].x, dd, b[16 * h + 2 * c]), 0.f) * dd;
            r[2 * c + 1] = fmaxf(fmaf(acc[c].y, dd, b[16 * h + 2 * c + 1]), 0.f) * dd;
        }
        A[(size_t)d * 2 + h] =
            make_uint4(pack_fp8x4(r[0],  r[1],  r[2],  r[3]),
                       pack_fp8x4(r[4],  r[5],  r[6],  r[7]),
                       pack_fp8x4(r[8],  r[9],  r[10], r[11]),
                       pack_fp8x4(r[12], r[13], r[14], r[15]));
    }
}

// ---- layer-2: parity-split pull(32 fp8) + fused gemm 32->48, vector csr ----
__global__ __launch_bounds__(256) void k_pullmm32(
        const uint4* __restrict__ Hp, const int* __restrict__ offs,
        const int* __restrict__ degi, const int* __restrict__ csr,
        const float* __restrict__ dis, const float* __restrict__ W,
        const float* __restrict__ b, unsigned* __restrict__ A, int n) {
    __shared__ float sW[32 * 48];    // 6 KB
    __shared__ float rows[64][33];   // 8.25 KB
    for (int i = threadIdx.x; i < 32 * 48; i += 256) sW[i] = W[i];
    const int group = threadIdx.x >> 2;
    const int h = threadIdx.x & 1;
    const int p = (threadIdx.x >> 1) & 1;
    const int d = blockIdx.x * 64 + group;
    if (d < n) {
        f32x2 acc[8];
        if (p == 0) {
            uint4 sv = Hp[(size_t)d * 2 + h];
            set2_fp8x4(sv.x, acc);     set2_fp8x4(sv.y, acc + 2);
            set2_fp8x4(sv.z, acc + 4); set2_fp8x4(sv.w, acc + 6);
        } else {
#pragma unroll
            for (int c = 0; c < 8; c++) { acc[c].x = 0.f; acc[c].y = 0.f; }
        }
        const int e0 = offs[d];
        const int end = e0 + degi[d];
        for (int w = e0; w < end; w += 8) {
            u4u ca = ldg4u(csr + w);
            u4u cb = ldg4u(csr + w + 4);
            unsigned cc[8] = {ca.x, ca.y, ca.z, ca.w, cb.x, cb.y, cb.z, cb.w};
            uint4 v[4];
#pragma unroll
            for (int i = 0; i < 4; i++) {
                int ee = w + p + 2 * i;
                uint4 t = Hp[(size_t)cc[p + 2 * i] * 2 + h];
                if (ee >= end) { t.x = 0u; t.y = 0u; t.z = 0u; t.w = 0u; }
                v[i] = t;
            }
#pragma unroll
            for (int i = 0; i < 4; i++) {
                acc2_fp8x4(v[i].x, acc);     acc2_fp8x4(v[i].y, acc + 2);
                acc2_fp8x4(v[i].z, acc + 4); acc2_fp8x4(v[i].w, acc + 6);
            }
        }
#pragma unroll
        for (int c = 0; c < 8; c++) {
            acc[c].x += __shfl_xor(acc[c].x, 2);
            acc[c].y += __shfl_xor(acc[c].y, 2);
        }
        if (p == 0) {
            const float dd = dis[d];
#pragma unroll
            for (int c = 0; c < 8; c++) {
                rows[group][16 * h + 2 * c]     = acc[c].x * dd;
                rows[group][16 * h + 2 * c + 1] = acc[c].y * dd;
            }
        }
    }
    __syncthreads();
    const int row0 = blockIdx.x * 64;
    const int nl = threadIdx.x & 63, cgb = threadIdx.x >> 6;  // row, col-block
    const int gr = row0 + nl;
    if (gr < n) {
        const float4* sW4 = (const float4*)sW;
        float s[3][4];
#pragma unroll
        for (int o = 0; o < 3; o++)
#pragma unroll
            for (int c = 0; c < 4; c++) s[o][c] = b[12 * cgb + 4 * o + c];
#pragma unroll 8
        for (int k = 0; k < 32; k++) {
            float rv = rows[nl][k];
#pragma unroll
            for (int o = 0; o < 3; o++) {
                float4 w = sW4[k * 12 + cgb * 3 + o];   // wave-uniform broadcast
                s[o][0] = fmaf(rv, w.x, s[o][0]);
                s[o][1] = fmaf(rv, w.y, s[o][1]);
                s[o][2] = fmaf(rv, w.z, s[o][2]);
                s[o][3] = fmaf(rv, w.w, s[o][3]);
            }
        }
        const float dd2 = dis[gr];
#pragma unroll
        for (int o = 0; o < 3; o++) {
            float r0 = fmaxf(s[o][0], 0.f) * dd2;
            float r1 = fmaxf(s[o][1], 0.f) * dd2;
            float r2 = fmaxf(s[o][2], 0.f) * dd2;
            float r3 = fmaxf(s[o][3], 0.f) * dd2;
            A[(size_t)gr * 12 + cgb * 3 + o] = pack_fp8x4(r0, r1, r2, r3);
        }
    }
}

// ---- layer-3: pull(48 fp8, 48B rows) + fused gemm 48->64, vector csr -------
__global__ __launch_bounds__(256) void k_pullmm48(
        const uint4* __restrict__ Hp,   // 3 x uint4 per row (48B)
        const int* __restrict__ offs,
        const int* __restrict__ degi, const int* __restrict__ csr,
        const float* __restrict__ dis, const float* __restrict__ W,
        const float* __restrict__ b, __half* __restrict__ A, int n) {
    __shared__ float sW[48 * 64];   // 12 KB
    __shared__ float rows[64][49];  // 12.25 KB
    for (int i = threadIdx.x; i < 48 * 64; i += 256) sW[i] = W[i];
    const int group = threadIdx.x >> 2, j0 = threadIdx.x & 3;
    const int d = blockIdx.x * 64 + group;
    if (d < n && j0 < 3) {          // lane 3 idles through the gather phase
        f32x2 acc[8];
        uint4 sv = Hp[(size_t)d * 3 + j0];
        set2_fp8x4(sv.x, acc);     set2_fp8x4(sv.y, acc + 2);
        set2_fp8x4(sv.z, acc + 4); set2_fp8x4(sv.w, acc + 6);
        const int e0 = offs[d];
        const int end = e0 + degi[d];
        for (int w = e0; w < end; w += 8) {
            u4u ca = ldg4u(csr + w);        // 2 dwordx4 replace 8 scalar loads
            u4u cb = ldg4u(csr + w + 4);
            unsigned cc[8] = {ca.x, ca.y, ca.z, ca.w, cb.x, cb.y, cb.z, cb.w};
            uint4 v[8];
#pragma unroll
            for (int i = 0; i < 8; i++) {
                uint4 t = Hp[(size_t)cc[i] * 3 + j0];
                if (w + i >= end) { t.x = 0u; t.y = 0u; t.z = 0u; t.w = 0u; }
                v[i] = t;
            }
#pragma unroll
            for (int i = 0; i < 8; i++) {
                acc2_fp8x4(v[i].x, acc);     acc2_fp8x4(v[i].y, acc + 2);
                acc2_fp8x4(v[i].z, acc + 4); acc2_fp8x4(v[i].w, acc + 6);
            }
        }
        const float dd = dis[d];
#pragma unroll
        for (int c = 0; c < 8; c++) {
            rows[group][16 * j0 + 2 * c]     = acc[c].x * dd;
            rows[group][16 * j0 + 2 * c + 1] = acc[c].y * dd;
        }
    }
    __syncthreads();
    const int row0 = blockIdx.x * 64;
    const int nl = threadIdx.x & 63, cgb = threadIdx.x >> 6;  // row, 16-col block
    const int gr = row0 + nl;
    if (gr < n) {
        const float4* sW4 = (const float4*)sW;
        float s[4][4];
#pragma unroll
        for (int o = 0; o < 4; o++)
#pragma unroll
            for (int c = 0; c < 4; c++) s[o][c] = b[16 * cgb + 4 * o + c];
#pragma unroll 8
        for (int k = 0; k < 48; k++) {
            float rv = rows[nl][k];
#pragma unroll
            for (int o = 0; o < 4; o++) {
                float4 w = sW4[k * 16 + cgb * 4 + o];   // wave-uniform broadcast
                s[o][0] = fmaf(rv, w.x, s[o][0]);
                s[o][1] = fmaf(rv, w.y, s[o][1]);
                s[o][2] = fmaf(rv, w.z, s[o][2]);
                s[o][3] = fmaf(rv, w.w, s[o][3]);
            }
        }
        uint4 q0, q1;
        q0.x = pkh2(s[0][0], s[0][1]); q0.y = pkh2(s[0][2], s[0][3]);
        q0.z = pkh2(s[1][0], s[1][1]); q0.w = pkh2(s[1][2], s[1][3]);
        q1.x = pkh2(s[2][0], s[2][1]); q1.y = pkh2(s[2][2], s[2][3]);
        q1.z = pkh2(s[3][0], s[3][1]); q1.w = pkh2(s[3][2], s[3][3]);
        ((uint4*)A)[(size_t)gr * 8 + cgb * 2]     = q0;
        ((uint4*)A)[(size_t)gr * 8 + cgb * 2 + 1] = q1;
    }
}

// ---- fused: bounds + mean-pool (32 rows in flight) + MLP head + softmax ----
__global__ __launch_bounds__(256) void k_poolhead(
        const __half* __restrict__ A3, const int* __restrict__ batch,
        const float* __restrict__ f1w, const float* __restrict__ f1b,
        const float* __restrict__ f2w, const float* __restrict__ f2b,
        float* __restrict__ out, int n, int ngr) {
    const int g = blockIdx.x;
    __shared__ int sb[2];
    if (threadIdx.x < 2) {
        int target = g + threadIdx.x;
        int lo = 0, hi = n;
        while (lo < hi) {
            int mid = (lo + hi) >> 1;
            if (batch[mid] < target) lo = mid + 1; else hi = mid;
        }
        sb[threadIdx.x] = lo;
    }
    __syncthreads();
    const int s = sb[0], e = sb[1];
    const int cg8 = threadIdx.x & 7;      // col-group (8 halves)
    const int rr  = threadIdx.x >> 3;     // 0..31 row offset
    float sum[8] = {0.f, 0.f, 0.f, 0.f, 0.f, 0.f, 0.f, 0.f};
    for (int node = s + rr; node < e; node += 32) {
        uint4 v = *(const uint4*)(A3 + (size_t)node * 64 + cg8 * 8);
        unsigned w[4] = {v.x, v.y, v.z, v.w};
#pragma unroll
        for (int h = 0; h < 4; h++) {
            __half2 h2 = *(__half2*)&w[h];
            float2 f = __half22float2(h2);
            sum[2 * h]     += fmaxf(f.x, 0.f);
            sum[2 * h + 1] += fmaxf(f.y, 0.f);
        }
    }
    __shared__ float red[32][64];
#pragma unroll
    for (int h = 0; h < 8; h++) red[rr][cg8 * 8 + h] = sum[h];
    __syncthreads();
    __shared__ float p[64], z[32], lg[16];
    const int t = threadIdx.x;
    if (t < 64) {
        float acc = 0.f;
#pragma unroll 8
        for (int r = 0; r < 32; r++) acc += red[r][t];
        p[t] = acc / fmaxf((float)(e - s), 1.f);
    }
    __syncthreads();
    if (t < 32) {
        float acc = f1b[t];
        for (int k = 0; k < 64; k++) acc = fmaf(p[k], f1w[k * 32 + t], acc);
        z[t] = fmaxf(acc, 0.f);
    }
    __syncthreads();
    if (t < 16) {
        float acc = f2b[t];
        for (int k = 0; k < 32; k++) acc = fmaf(z[k], f2w[k * 16 + t], acc);
        lg[t] = acc;
    }
    __syncthreads();
    if (t < 16) {
        float m = lg[0];
        for (int i = 1; i < 16; i++) m = fmaxf(m, lg[i]);
        float sden = 0.f;
        for (int i = 0; i < 16; i++) sden += expf(lg[i] - m);
        out[g * 16 + t] = expf(lg[t] - m) / sden;
    }
}

extern "C" void kernel_launch(void* const* d_in, const int* in_sizes, int n_in,
                              void* d_out, int out_size, void* d_ws, size_t ws_size,
                              hipStream_t stream) {
    (void)in_sizes; (void)n_in; (void)out_size; (void)ws_size;
    const float* x     = (const float*)d_in[0];
    const int*   ei    = (const int*)d_in[1];
    const int*   batch = (const int*)d_in[2];
    const float* W1 = (const float*)d_in[3];
    const float* b1 = (const float*)d_in[4];
    const float* W2 = (const float*)d_in[5];  const float* b2 = (const float*)d_in[6];
    const float* W3 = (const float*)d_in[7];  const float* b3 = (const float*)d_in[8];
    const float* f1w = (const float*)d_in[9]; const float* f1b = (const float*)d_in[10];
    const float* f2w = (const float*)d_in[11];const float* f2b = (const float*)d_in[12];
    float* out = (float*)d_out;

    const int* src = ei;
    const int* dst = ei + NE;

    // Workspace (~40 MB):
    //   tmp uint[NE] (12.8MB)  aliased with  A3 fp16[NN*64] (12.8MB)
    //   H1 fp8[NN*32] (3.2MB), H2 fp8[NN*32] (3.2MB), H3 fp8[NN*48] (4.8MB)
    //   csr padded +16 entries (vector csr loads read up to csr[NE+6])
    float* ws = (float*)d_ws;
    size_t o = 0;
    float* dis    = ws + o; o += NN;
    int*   degi   = (int*)(ws + o); o += NN;
    int*   offs   = (int*)(ws + o); o += NN;
    int*   cntC   = (int*)(ws + o); o += 76640;       // NCNT padded to /16
    int*   sc     = (int*)(ws + o); o += 76640;
    int*   bsum   = (int*)(ws + o); o += 48;
    int*   csr    = (int*)(ws + o); o += NE + 16;     // +pad
    unsigned* TA  = (unsigned*)(ws + o); o += NE;     // tmp | A3
    unsigned* H1  = (unsigned*)(ws + o); o += NN * 8;
    unsigned* H2  = (unsigned*)(ws + o); o += NN * 8;
    unsigned* H3  = (unsigned*)(ws + o); o += NN * 12;  // 48B rows, 16B aligned

    unsigned* tmp = (unsigned*)TA;
    __half*   A3  = (__half*)TA;

    // CSR build: coarse counting sort (196 bins x 512 nodes) + in-LDS sub-sort
    k_histC<<<NCH, 256, 0, stream>>>((const int4*)dst, cntC, NE / 4);
    k_scanA<<<NSB, 256, 0, stream>>>(cntC, sc, bsum, NCNT);
    k_scanB<<<1, 256, 0, stream>>>(bsum, NSB);
    k_scatC<<<NCH, 256, 0, stream>>>((const int4*)src, (const int4*)dst,
                                     sc, bsum, tmp, NE / 4);
    k_fill512<<<NCB, 1024, 0, stream>>>(tmp, sc, bsum, csr, degi, offs, dis, NN, NE);

    const int PGRID = (NN + 63) / 64;  // 1563: 64 nodes/block, 4 lanes/node

    // Layer 1: transform-first GEMM (128->32) -> fp8 H1; pull -> fp8 H2
    k_gemm1<<<(NN + 31) / 32, 256, 0, stream>>>(x, W1, dis, H1, NN);
    k_pull2<<<PGRID, 256, 0, stream>>>((const uint4*)H1, offs, degi, csr, dis, b1,
                                       (uint4*)H2, NN);

    // Layer 2: pull(32 fp8) + fused gemm 32->48 -> fp8 H3 (48B rows)
    k_pullmm32<<<PGRID, 256, 0, stream>>>((const uint4*)H2, offs, degi, csr, dis,
                                          W2, b2, H3, NN);

    // Layer 3: pull(48 fp8) + fused gemm 48->64 -> A3 fp16
    k_pullmm48<<<PGRID, 256, 0, stream>>>(
        (const uint4*)H3, offs, degi, csr, dis, W3, b3, A3, NN);

    // Fused bounds + pool + head
    k_poolhead<<<NG, 256, 0, stream>>>(A3, batch, f1w, f1b, f2w, f2b, out, NN, NG);
}